// Round 5
// baseline (463.272 us; speedup 1.0000x reference)
//
#include <hip/hip_runtime.h>
#include <hip/hip_bf16.h>

#define N_NODES_C 100000
#define FEATS 128
#define SH 10             // bucket shift: 1024 nodes per bucket
#define NBK 128           // padded bucket count (active: 98)
#define PB  256           // partition blocks
#define NHIST (NBK * PB)  // 32768
#define CAST_BLOCKS 12500 // (100000*128/4)/256

typedef unsigned int uint32;
typedef __bf16 bf16_t;
typedef bf16_t bf16x8 __attribute__((ext_vector_type(8)));
typedef float f32x4 __attribute__((ext_vector_type(4)));

union Frag { uint4 u; bf16x8 v; };

__device__ __forceinline__ unsigned short f32_to_bf16_bits(float f) {
    uint32 u = __float_as_uint(f);
    u += 0x7fffu + ((u >> 16) & 1u);   // round-to-nearest-even (finite values)
    return (unsigned short)(u >> 16);
}
__device__ __forceinline__ float bf16_lo(uint32 p) { return __uint_as_float(p << 16); }
__device__ __forceinline__ float bf16_hi(uint32 p) { return __uint_as_float(p & 0xffff0000u); }

// ---------------- Fused prep: part_count + wtprep x2 + cast ----------------
__global__ __launch_bounds__(256) void prep_fused(
    const int* __restrict__ dst, int* __restrict__ gHist, int nE, int chunk,
    const float4* __restrict__ emb4, unsigned short* __restrict__ hb0, int n4,
    const float* __restrict__ W1s, const float* __restrict__ W1n, unsigned short* __restrict__ wt1,
    const float* __restrict__ W2s, const float* __restrict__ W2n, unsigned short* __restrict__ wt2)
{
    __shared__ int h[NBK];
    const int b = blockIdx.x;
    const int tid = threadIdx.x;

    if (b < PB) {
        // --- bucket histogram over this block's edge chunk ---
        if (tid < NBK) h[tid] = 0;
        __syncthreads();
        const int b0 = b * chunk;
        const int e1 = min(b0 + chunk, nE);
        for (int e = b0 + tid; e < e1; e += 256)
            atomicAdd(&h[dst[e] >> SH], 1);
        __syncthreads();
        if (tid < NBK) gHist[tid * PB + b] = h[tid];
    } else if (b < PB + 32) {
        // --- weight pre-swizzle into B-fragment order ---
        // wt[(f*64+l)*8+j] = W[k][n], f=nt*8+ks, n=nt*16+(l&15), k=ks*32+(l>>4)*8+j
        const int which = (b - PB) >> 4;                 // 0 -> layer1, 1 -> layer2
        const float* Ws = which ? W2s : W1s;
        const float* Wn = which ? W2n : W1n;
        unsigned short* wt = which ? wt2 : wt1;
        int gid = ((b - PB) & 15) * 256 + tid;           // 0..4095
        int frag = gid >> 6, lane = gid & 63;
        int nt = frag >> 3, ks = frag & 7;
        int n = nt * 16 + (lane & 15);
        int kbase = ks * 32 + (lane >> 4) * 8;
        union { unsigned short s[8]; uint4 u; } o;
#pragma unroll
        for (int j = 0; j < 8; ++j) {
            int k = kbase + j;
            float v = (k < 128) ? Ws[(size_t)k * FEATS + n] : Wn[(size_t)(k - 128) * FEATS + n];
            o.s[j] = f32_to_bf16_bits(v);
        }
        *(uint4*)(wt + (size_t)gid * 8) = o.u;
    } else {
        // --- fp32 -> bf16 node-table cast ---
        int i = (b - PB - 32) * 256 + tid;
        if (i >= n4) return;
        float4 v = emb4[i];
        union { unsigned short s[4]; uint2 u; } o;
        o.s[0] = f32_to_bf16_bits(v.x);
        o.s[1] = f32_to_bf16_bits(v.y);
        o.s[2] = f32_to_bf16_bits(v.z);
        o.s[3] = f32_to_bf16_bits(v.w);
        *(uint2*)(hb0 + (size_t)i * 4) = o.u;
    }
}

// ---------------- One-dispatch exclusive scan of gHist (32768 ints) ----------------
__global__ __launch_bounds__(1024) void scan_one(int* __restrict__ g) {
    __shared__ int ss[1024];
    const int tid = threadIdx.x;
    const int base = tid * 32;
    int pref[32];
    int sum = 0;
#pragma unroll
    for (int j = 0; j < 32; ++j) {
        int v = g[base + j];
        pref[j] = sum;
        sum += v;
    }
    ss[tid] = sum;
    __syncthreads();
    for (int d = 1; d < 1024; d <<= 1) {
        int t = (tid >= d) ? ss[tid - d] : 0;
        __syncthreads();
        ss[tid] += t;
        __syncthreads();
    }
    int ex = ss[tid] - sum;
#pragma unroll
    for (int j = 0; j < 32; ++j)
        g[base + j] = ex + pref[j];
}

// ---------------- P2: scatter packed (src | localdst<<17) into bucketed ebuf ----------------
__global__ __launch_bounds__(256) void part_scatter(const int* __restrict__ src,
                                                    const int* __restrict__ dst,
                                                    const int* __restrict__ gScan,
                                                    uint32* __restrict__ ebuf,
                                                    int nE, int chunk) {
    __shared__ int cur[NBK];
    const int tid = threadIdx.x;
    if (tid < NBK) cur[tid] = gScan[tid * PB + blockIdx.x];
    __syncthreads();
    const int b0 = blockIdx.x * chunk;
    const int e1 = min(b0 + chunk, nE);
    for (int e = b0 + tid; e < e1; e += 256) {
        int d = dst[e];
        int pos = atomicAdd(&cur[d >> SH], 1);
        ebuf[pos] = (uint32)src[e] | ((uint32)(d & ((1 << SH) - 1)) << 17);
    }
}

// ---------------- P3: per-bucket CSR finalize ----------------
__global__ __launch_bounds__(1024) void bucket_csr(const uint32* __restrict__ ebuf,
                                                   const int* __restrict__ gScan,
                                                   int* __restrict__ off,
                                                   int* __restrict__ csr,
                                                   int nE) {
    __shared__ int cnt[1 << SH];
    __shared__ int ss[1 << SH];
    const int b = blockIdx.x;
    const int tid = threadIdx.x;
    const int start = gScan[b * PB];
    const int end = gScan[(b + 1) * PB];
    const int nodeBase = b << SH;
    cnt[tid] = 0;
    __syncthreads();
    for (int e = start + tid; e < end; e += 1024)
        atomicAdd(&cnt[ebuf[e] >> 17], 1);
    __syncthreads();
    int own = cnt[tid];
    ss[tid] = own;
    __syncthreads();
    for (int d = 1; d < 1024; d <<= 1) {
        int t = (tid >= d) ? ss[tid - d] : 0;
        __syncthreads();
        ss[tid] += t;
        __syncthreads();
    }
    int ex = ss[tid] - own;
    cnt[tid] = ex;                     // becomes placement cursor
    int node = nodeBase + tid;
    if (node < N_NODES_C) off[node] = start + ex;
    if (b == gridDim.x - 1 && tid == 0) off[N_NODES_C] = nE;
    __syncthreads();
    for (int e = start + tid; e < end; e += 1024) {
        uint32 p = ebuf[e];
        int pos = atomicAdd(&cnt[p >> 17], 1);
        csr[start + pos] = (int)(p & 0x1FFFFu);
    }
}

// ---------------- Fused gather-mean + MFMA SAGE GEMM ----------------
// Block = 64 nodes, 4 waves. Phase 1: each wave gathers means for its 16 nodes
// into wave-private LDS rows (no barrier needed). Phase 2: per-wave 16x128 MFMA
// GEMM, K=256 = [self (global) | mean (LDS)], weights pre-swizzled B-frags.
__global__ __launch_bounds__(256) void sage_fused(const unsigned short* __restrict__ HB,
                                                  const int* __restrict__ csr,
                                                  const int* __restrict__ off,
                                                  const unsigned short* __restrict__ WT,
                                                  const float* __restrict__ bias,
                                                  void* __restrict__ OUTP,
                                                  int nNodes, int mode) {
    __shared__ uint32 smean[64][68];   // stride 68: 16B-aligned rows, bank spread
    const int tid = threadIdx.x;
    const int wave = tid >> 6;
    const int lane = tid & 63;
    const int blockBase = blockIdx.x * 64;
    const uint32* h32 = (const uint32*)HB;

    // ---- Phase 1: gather mean (lane covers cols 2*lane, 2*lane+1) ----
    for (int i = 0; i < 16; ++i) {
        const int local = wave * 16 + i;
        const int node = blockBase + local;
        int start = 0, end = 0;
        if (node < nNodes) { start = off[node]; end = off[node + 1]; }
        float a0 = 0.f, a1 = 0.f;
        int e = start;
        for (; e + 8 <= end; e += 8) {
            int s[8];
#pragma unroll
            for (int j = 0; j < 8; ++j) s[j] = csr[e + j];
            uint32 u[8];
#pragma unroll
            for (int j = 0; j < 8; ++j) u[j] = h32[(size_t)s[j] * 64 + lane];
#pragma unroll
            for (int j = 0; j < 8; ++j) { a0 += bf16_lo(u[j]); a1 += bf16_hi(u[j]); }
        }
        for (; e < end; ++e) {
            uint32 u = h32[(size_t)csr[e] * 64 + lane];
            a0 += bf16_lo(u); a1 += bf16_hi(u);
        }
        const int deg = end - start;
        const float invd = (deg > 0) ? (1.f / (float)deg) : 0.f;
        smean[local][lane] = ((uint32)f32_to_bf16_bits(a1 * invd) << 16)
                           | (uint32)f32_to_bf16_bits(a0 * invd);
    }
    // no __syncthreads: LDS rows are wave-private (written and read by same wave)

    // ---- Phase 2: MFMA GEMM ----
    const int waveBase = blockBase + wave * 16;
    const int m = lane & 15;
    const int quad = lane >> 4;
    int arow = waveBase + m;
    if (arow >= nNodes) arow = nNodes - 1;            // clamp loads; stores guarded
    const uint4* hrow = (const uint4*)(HB + (size_t)arow * FEATS);

    Frag a[8];
#pragma unroll
    for (int ks = 0; ks < 4; ++ks) a[ks].u = hrow[ks * 4 + quad];
#pragma unroll
    for (int ks = 0; ks < 4; ++ks)
        a[ks + 4].u = *(const uint4*)&smean[wave * 16 + m][ks * 16 + quad * 4];

    const uint4* wt4 = (const uint4*)WT;
    f32x4 acc[8];
#pragma unroll
    for (int nt = 0; nt < 8; ++nt) acc[nt] = (f32x4){0.f, 0.f, 0.f, 0.f};

#pragma unroll
    for (int ks = 0; ks < 8; ++ks) {
#pragma unroll
        for (int nt = 0; nt < 8; ++nt) {
            Frag b;
            b.u = wt4[(size_t)(nt * 8 + ks) * 64 + lane];
            acc[nt] = __builtin_amdgcn_mfma_f32_16x16x32_bf16(a[ks].v, b.v, acc[nt], 0, 0, 0);
        }
    }

#pragma unroll
    for (int nt = 0; nt < 8; ++nt) {
        const int col = nt * 16 + m;
        const float bv = bias[col];
#pragma unroll
        for (int r = 0; r < 4; ++r) {
            const int grow = waveBase + quad * 4 + r;  // C/D: row=(lane>>4)*4+reg, col=lane&15
            if (grow >= nNodes) continue;
            float v = acc[nt][r] + bv;
            if (mode) {
                v = v > 0.f ? v : 0.2f * v;
                ((unsigned short*)OUTP)[(size_t)grow * FEATS + col] = f32_to_bf16_bits(v);
            } else {
                ((float*)OUTP)[(size_t)grow * FEATS + col] = v;
            }
        }
    }
}

extern "C" void kernel_launch(void* const* d_in, const int* in_sizes, int n_in,
                              void* d_out, int out_size, void* d_ws, size_t ws_size,
                              hipStream_t stream) {
    const float* emb = (const float*)d_in[0];
    const float* W1s = (const float*)d_in[1];
    const float* W1n = (const float*)d_in[2];
    const float* b1  = (const float*)d_in[3];
    const float* W2s = (const float*)d_in[4];
    const float* W2n = (const float*)d_in[5];
    const float* b2  = (const float*)d_in[6];
    const int*   edg = (const int*)d_in[7];

    const int nE = in_sizes[7] / 2;
    const int* src = edg;
    const int* dst = edg + nE;

    const int chunk = (nE + PB - 1) / PB;            // 6250
    const int nActB = (N_NODES_C + (1 << SH) - 1) >> SH;   // 98
    const int n4 = N_NODES_C * FEATS / 4;            // 3,200,000

    const size_t bfTab = (size_t)N_NODES_C * FEATS * sizeof(unsigned short);  // 25.6 MB

    char* ws = (char*)d_ws;
    int* off      = (int*)(ws);                      // 400 KB + 4
    int* gHist    = (int*)(ws + (512 << 10));        // 128 KB
    int* csr      = (int*)(ws + (1 << 20));          // 6.4 MB
    uint32* ebuf  = (uint32*)(ws + (8 << 20));       // 6.4 MB
    unsigned short* wt1 = (unsigned short*)(ws + (15 << 20));   // 64 KB
    unsigned short* wt2 = (unsigned short*)(ws + (15 << 20) + (64 << 10));
    unsigned short* hb0 = (unsigned short*)(ws + (16 << 20));   // 25.6 MB
    unsigned short* h1b = (unsigned short*)((char*)hb0 + bfTab);
    float* out = (float*)d_out;

    // ---- 1: fused prep (bucket histogram + weight swizzle + bf16 cast) ----
    prep_fused<<<PB + 32 + CAST_BLOCKS, 256, 0, stream>>>(
        dst, gHist, nE, chunk, (const float4*)emb, hb0, n4,
        W1s, W1n, wt1, W2s, W2n, wt2);

    // ---- 2-4: CSR build ----
    scan_one<<<1, 1024, 0, stream>>>(gHist);
    part_scatter<<<PB, 256, 0, stream>>>(src, dst, gHist, ebuf, nE, chunk);
    bucket_csr<<<nActB, 1024, 0, stream>>>(ebuf, gHist, off, csr, nE);

    // ---- 5-6: fused layers ----
    const int fusedBlocks = (N_NODES_C + 63) / 64;   // 1563
    sage_fused<<<fusedBlocks, 256, 0, stream>>>(hb0, csr, off, wt1, b1, h1b, N_NODES_C, 1);
    sage_fused<<<fusedBlocks, 256, 0, stream>>>(h1b, csr, off, wt2, b2, out, N_NODES_C, 0);
}

// Round 6
// 378.615 us; speedup vs baseline: 1.2236x; 1.2236x over previous
//
#include <hip/hip_runtime.h>
#include <hip/hip_bf16.h>

#define N_NODES_C 100000
#define FEATS 128
#define SH 10             // bucket shift: 1024 nodes per bucket
#define NBK 128           // padded bucket count (active: 98)
#define PB  256           // partition blocks
#define CAST_BLOCKS 12500 // (100000*128/4)/256

typedef unsigned int uint32;
typedef __bf16 bf16_t;
typedef bf16_t bf16x8 __attribute__((ext_vector_type(8)));
typedef float f32x4 __attribute__((ext_vector_type(4)));

union Frag { uint4 u; bf16x8 v; };

__device__ __forceinline__ unsigned short f32_to_bf16_bits(float f) {
    uint32 u = __float_as_uint(f);
    u += 0x7fffu + ((u >> 16) & 1u);   // round-to-nearest-even (finite values)
    return (unsigned short)(u >> 16);
}
__device__ __forceinline__ float bf16_lo(uint32 p) { return __uint_as_float(p << 16); }
__device__ __forceinline__ float bf16_hi(uint32 p) { return __uint_as_float(p & 0xffff0000u); }

// ---------------- Fused prep: part_count + wtprep x2 + cast ----------------
__global__ __launch_bounds__(256) void prep_fused(
    const int* __restrict__ dst, int* __restrict__ gHist, int nE, int chunk,
    const float4* __restrict__ emb4, unsigned short* __restrict__ hb0, int n4,
    const float* __restrict__ W1s, const float* __restrict__ W1n, unsigned short* __restrict__ wt1,
    const float* __restrict__ W2s, const float* __restrict__ W2n, unsigned short* __restrict__ wt2)
{
    __shared__ int h[NBK];
    const int b = blockIdx.x;
    const int tid = threadIdx.x;

    if (b < PB) {
        // --- bucket histogram over this block's edge chunk ---
        if (tid < NBK) h[tid] = 0;
        __syncthreads();
        const int b0 = b * chunk;
        const int e1 = min(b0 + chunk, nE);
        for (int e = b0 + tid; e < e1; e += 256)
            atomicAdd(&h[dst[e] >> SH], 1);
        __syncthreads();
        if (tid < NBK) gHist[tid * PB + b] = h[tid];
    } else if (b < PB + 32) {
        // --- weight pre-swizzle into B-fragment order ---
        // wt[(f*64+l)*8+j] = W[k][n], f=nt*8+ks, n=nt*16+(l&15), k=ks*32+(l>>4)*8+j
        const int which = (b - PB) >> 4;                 // 0 -> layer1, 1 -> layer2
        const float* Ws = which ? W2s : W1s;
        const float* Wn = which ? W2n : W1n;
        unsigned short* wt = which ? wt2 : wt1;
        int gid = ((b - PB) & 15) * 256 + tid;           // 0..4095
        int frag = gid >> 6, lane = gid & 63;
        int nt = frag >> 3, ks = frag & 7;
        int n = nt * 16 + (lane & 15);
        int kbase = ks * 32 + (lane >> 4) * 8;
        union { unsigned short s[8]; uint4 u; } o;
#pragma unroll
        for (int j = 0; j < 8; ++j) {
            int k = kbase + j;
            float v = (k < 128) ? Ws[(size_t)k * FEATS + n] : Wn[(size_t)(k - 128) * FEATS + n];
            o.s[j] = f32_to_bf16_bits(v);
        }
        *(uint4*)(wt + (size_t)gid * 8) = o.u;
    } else {
        // --- fp32 -> bf16 node-table cast ---
        int i = (b - PB - 32) * 256 + tid;
        if (i >= n4) return;
        float4 v = emb4[i];
        union { unsigned short s[4]; uint2 u; } o;
        o.s[0] = f32_to_bf16_bits(v.x);
        o.s[1] = f32_to_bf16_bits(v.y);
        o.s[2] = f32_to_bf16_bits(v.z);
        o.s[3] = f32_to_bf16_bits(v.w);
        *(uint2*)(hb0 + (size_t)i * 4) = o.u;
    }
}

// ---------------- One-dispatch exclusive scan of gHist (32768 ints) ----------------
__global__ __launch_bounds__(1024) void scan_one(int* __restrict__ g) {
    __shared__ int ss[1024];
    const int tid = threadIdx.x;
    const int base = tid * 32;
    int pref[32];
    int sum = 0;
#pragma unroll
    for (int j = 0; j < 32; ++j) {
        int v = g[base + j];
        pref[j] = sum;
        sum += v;
    }
    ss[tid] = sum;
    __syncthreads();
    for (int d = 1; d < 1024; d <<= 1) {
        int t = (tid >= d) ? ss[tid - d] : 0;
        __syncthreads();
        ss[tid] += t;
        __syncthreads();
    }
    int ex = ss[tid] - sum;
#pragma unroll
    for (int j = 0; j < 32; ++j)
        g[base + j] = ex + pref[j];
}

// ---------------- P2: scatter packed (src | localdst<<17) into bucketed ebuf ----------------
__global__ __launch_bounds__(256) void part_scatter(const int* __restrict__ src,
                                                    const int* __restrict__ dst,
                                                    const int* __restrict__ gScan,
                                                    uint32* __restrict__ ebuf,
                                                    int nE, int chunk) {
    __shared__ int cur[NBK];
    const int tid = threadIdx.x;
    if (tid < NBK) cur[tid] = gScan[tid * PB + blockIdx.x];
    __syncthreads();
    const int b0 = blockIdx.x * chunk;
    const int e1 = min(b0 + chunk, nE);
    for (int e = b0 + tid; e < e1; e += 256) {
        int d = dst[e];
        int pos = atomicAdd(&cur[d >> SH], 1);
        ebuf[pos] = (uint32)src[e] | ((uint32)(d & ((1 << SH) - 1)) << 17);
    }
}

// ---------------- P3: per-bucket CSR finalize ----------------
__global__ __launch_bounds__(1024) void bucket_csr(const uint32* __restrict__ ebuf,
                                                   const int* __restrict__ gScan,
                                                   int* __restrict__ off,
                                                   int* __restrict__ csr,
                                                   int nE) {
    __shared__ int cnt[1 << SH];
    __shared__ int ss[1 << SH];
    const int b = blockIdx.x;
    const int tid = threadIdx.x;
    const int start = gScan[b * PB];
    const int end = gScan[(b + 1) * PB];
    const int nodeBase = b << SH;
    cnt[tid] = 0;
    __syncthreads();
    for (int e = start + tid; e < end; e += 1024)
        atomicAdd(&cnt[ebuf[e] >> 17], 1);
    __syncthreads();
    int own = cnt[tid];
    ss[tid] = own;
    __syncthreads();
    for (int d = 1; d < 1024; d <<= 1) {
        int t = (tid >= d) ? ss[tid - d] : 0;
        __syncthreads();
        ss[tid] += t;
        __syncthreads();
    }
    int ex = ss[tid] - own;
    cnt[tid] = ex;                     // becomes placement cursor
    int node = nodeBase + tid;
    if (node < N_NODES_C) off[node] = start + ex;
    if (b == gridDim.x - 1 && tid == 0) off[N_NODES_C] = nE;
    __syncthreads();
    for (int e = start + tid; e < end; e += 1024) {
        uint32 p = ebuf[e];
        int pos = atomicAdd(&cnt[p >> 17], 1);
        csr[start + pos] = (int)(p & 0x1FFFFu);
    }
}

// ---------------- Gather (mean aggregation over bf16 table) ----------------
// 4 nodes per 256-thread block; one wave per node, bf16x2 per lane.
// One wave per node keeps 100K waves in flight — the latency-hiding resource
// (R4 fusion cut this 16x and regressed; do not re-fuse).
__global__ __launch_bounds__(256) void gather_mean_bf16(const unsigned short* __restrict__ hb,
                                                        const int* __restrict__ csr,
                                                        const int* __restrict__ off,
                                                        unsigned short* __restrict__ meanb,
                                                        int nNodes) {
    const int node = blockIdx.x * 4 + (threadIdx.x >> 6);
    const int lane = threadIdx.x & 63;
    if (node >= nNodes) return;
    const int start = off[node];
    const int end = off[node + 1];
    const uint32* h32 = (const uint32*)hb;   // row = 64 uints
    float a0 = 0.f, a1 = 0.f;
    int e = start;
    for (; e + 8 <= end; e += 8) {
        int s[8];
#pragma unroll
        for (int j = 0; j < 8; ++j) s[j] = csr[e + j];
        uint32 u[8];
#pragma unroll
        for (int j = 0; j < 8; ++j) u[j] = h32[(size_t)s[j] * 64 + lane];
#pragma unroll
        for (int j = 0; j < 8; ++j) { a0 += bf16_lo(u[j]); a1 += bf16_hi(u[j]); }
    }
    for (; e < end; ++e) {
        uint32 u = h32[(size_t)csr[e] * 64 + lane];
        a0 += bf16_lo(u); a1 += bf16_hi(u);
    }
    const int deg = end - start;
    const float invd = (deg > 0) ? (1.f / (float)deg) : 0.f;
    uint32 o = ((uint32)f32_to_bf16_bits(a1 * invd) << 16) | (uint32)f32_to_bf16_bits(a0 * invd);
    ((uint32*)meanb)[(size_t)node * 64 + lane] = o;
}

// ---------------- MFMA SAGE GEMM (LDS-free) ----------------
// Per wave: 16-row stripe x 128 cols, K=256 = [HB | MB].
__global__ __launch_bounds__(256) void sage_gemm_mfma(const unsigned short* __restrict__ HB,
                                                      const unsigned short* __restrict__ MB,
                                                      const unsigned short* __restrict__ WT,
                                                      const float* __restrict__ bias,
                                                      void* __restrict__ OUTP,
                                                      int nNodes, int mode) {
    const int wave = threadIdx.x >> 6;
    const int lane = threadIdx.x & 63;
    const int waveBase = blockIdx.x * 64 + wave * 16;
    const int m = lane & 15;
    const int quad = lane >> 4;

    int arow = waveBase + m;
    if (arow >= nNodes) arow = nNodes - 1;           // clamp loads; stores guarded below
    const uint4* hrow = (const uint4*)(HB + (size_t)arow * FEATS);
    const uint4* mrow = (const uint4*)(MB + (size_t)arow * FEATS);

    Frag a[8];
#pragma unroll
    for (int ks = 0; ks < 4; ++ks) a[ks].u = hrow[ks * 4 + quad];
#pragma unroll
    for (int ks = 0; ks < 4; ++ks) a[ks + 4].u = mrow[ks * 4 + quad];

    const uint4* wt4 = (const uint4*)WT;
    f32x4 acc[8];
#pragma unroll
    for (int nt = 0; nt < 8; ++nt) acc[nt] = (f32x4){0.f, 0.f, 0.f, 0.f};

#pragma unroll
    for (int ks = 0; ks < 8; ++ks) {
#pragma unroll
        for (int nt = 0; nt < 8; ++nt) {
            Frag b;
            b.u = wt4[(size_t)(nt * 8 + ks) * 64 + lane];
            acc[nt] = __builtin_amdgcn_mfma_f32_16x16x32_bf16(a[ks].v, b.v, acc[nt], 0, 0, 0);
        }
    }

#pragma unroll
    for (int nt = 0; nt < 8; ++nt) {
        const int col = nt * 16 + m;
        const float bv = bias[col];
#pragma unroll
        for (int r = 0; r < 4; ++r) {
            const int grow = waveBase + quad * 4 + r;   // C/D: row=(lane>>4)*4+reg, col=lane&15
            if (grow >= nNodes) continue;
            float v = acc[nt][r] + bv;
            if (mode) {
                v = v > 0.f ? v : 0.2f * v;
                ((unsigned short*)OUTP)[(size_t)grow * FEATS + col] = f32_to_bf16_bits(v);
            } else {
                ((float*)OUTP)[(size_t)grow * FEATS + col] = v;
            }
        }
    }
}

extern "C" void kernel_launch(void* const* d_in, const int* in_sizes, int n_in,
                              void* d_out, int out_size, void* d_ws, size_t ws_size,
                              hipStream_t stream) {
    const float* emb = (const float*)d_in[0];
    const float* W1s = (const float*)d_in[1];
    const float* W1n = (const float*)d_in[2];
    const float* b1  = (const float*)d_in[3];
    const float* W2s = (const float*)d_in[4];
    const float* W2n = (const float*)d_in[5];
    const float* b2  = (const float*)d_in[6];
    const int*   edg = (const int*)d_in[7];

    const int nE = in_sizes[7] / 2;
    const int* src = edg;
    const int* dst = edg + nE;

    const int chunk = (nE + PB - 1) / PB;            // 6250
    const int nActB = (N_NODES_C + (1 << SH) - 1) >> SH;   // 98
    const int n4 = N_NODES_C * FEATS / 4;            // 3,200,000

    const size_t bfTab = (size_t)N_NODES_C * FEATS * sizeof(unsigned short);  // 25.6 MB

    char* ws = (char*)d_ws;
    int* off      = (int*)(ws);                      // 400 KB + 4
    int* gHist    = (int*)(ws + (512 << 10));        // 128 KB
    int* csr      = (int*)(ws + (1 << 20));          // 6.4 MB
    uint32* ebuf  = (uint32*)(ws + (8 << 20));       // 6.4 MB
    unsigned short* wt1 = (unsigned short*)(ws + (15 << 20));   // 64 KB
    unsigned short* wt2 = (unsigned short*)(ws + (15 << 20) + (64 << 10));
    unsigned short* hb0 = (unsigned short*)(ws + (16 << 20));   // 25.6 MB
    unsigned short* h1b = (unsigned short*)((char*)hb0 + bfTab);
    unsigned short* mnb = (unsigned short*)((char*)h1b + bfTab);
    float* out = (float*)d_out;

    // ---- 1: fused prep (bucket histogram + weight swizzle + bf16 cast) ----
    prep_fused<<<PB + 32 + CAST_BLOCKS, 256, 0, stream>>>(
        dst, gHist, nE, chunk, (const float4*)emb, hb0, n4,
        W1s, W1n, wt1, W2s, W2n, wt2);

    // ---- 2-4: CSR build ----
    scan_one<<<1, 1024, 0, stream>>>(gHist);
    part_scatter<<<PB, 256, 0, stream>>>(src, dst, gHist, ebuf, nE, chunk);
    bucket_csr<<<nActB, 1024, 0, stream>>>(ebuf, gHist, off, csr, nE);

    // ---- 5-8: layers (separate gather + gemm; see R4 post-mortem) ----
    const int gatherBlocks = (N_NODES_C + 3) / 4;    // 25000
    const int gemmBlocks = (N_NODES_C + 63) / 64;    // 1563

    gather_mean_bf16<<<gatherBlocks, 256, 0, stream>>>(hb0, csr, off, mnb, N_NODES_C);
    sage_gemm_mfma<<<gemmBlocks, 256, 0, stream>>>(hb0, mnb, wt1, b1, h1b, N_NODES_C, 1);

    gather_mean_bf16<<<gatherBlocks, 256, 0, stream>>>(h1b, csr, off, mnb, N_NODES_C);
    sage_gemm_mfma<<<gemmBlocks, 256, 0, stream>>>(h1b, mnb, wt2, b2, out, N_NODES_C, 0);
}